// Round 9
// baseline (268.063 us; speedup 1.0000x reference)
//
#include <hip/hip_runtime.h>
#include <cstdint>

#define S_LEN 1024
#define C_DIM 2048
#define NH    16
#define NHK   4
#define HD    128
#define ROT   32
#define SCALE 0.08838834764831845f  // 1/sqrt(128)

typedef __bf16 bf16x8 __attribute__((ext_vector_type(8)));
typedef float floatx4 __attribute__((ext_vector_type(4)));
typedef float floatx16 __attribute__((ext_vector_type(16)));
typedef unsigned short ushortx8 __attribute__((ext_vector_type(8)));

__device__ __forceinline__ unsigned short f2bf(float f) {
  union { float f; uint32_t u; } x; x.f = f;
  uint32_t r = (x.u + 0x7fffu + ((x.u >> 16) & 1u)) >> 16;
  return (unsigned short)r;
}
__device__ __forceinline__ float bf2f(unsigned short v) {
  union { uint32_t u; float f; } x; x.u = (uint32_t)v << 16; return x.f;
}

__device__ __forceinline__ void async_copy16(const unsigned short* g, unsigned short* l) {
  __builtin_amdgcn_global_load_lds(
      (const __attribute__((address_space(1))) void*)g,
      (__attribute__((address_space(3))) void*)l,
      16, 0, 0);
}

// ---------------- fused weight cast f32 -> bf16 ----------------
__global__ void cast_all_kernel(const float* __restrict__ qw, const float* __restrict__ kw,
                                const float* __restrict__ vw, const float* __restrict__ ow,
                                unsigned short* __restrict__ out) {
  const int NQ = 4096 * 2048 / 4, NK = 512 * 2048 / 4, NV = 512 * 2048 / 4;
  int i = blockIdx.x * blockDim.x + threadIdx.x;
  const float* src; int j;
  if (i < NQ) { src = qw; j = i; }
  else if (i < NQ + NK) { src = kw; j = i - NQ; }
  else if (i < NQ + NK + NV) { src = vw; j = i - NQ - NK; }
  else { src = ow; j = i - NQ - NK - NV; }
  float4 v = ((const float4*)src)[j];
  ushort4 o;
  o.x = f2bf(v.x); o.y = f2bf(v.y); o.z = f2bf(v.z); o.w = f2bf(v.w);
  ((ushort4*)out)[i] = o;
}

// ---------------- transpose + cast x (C,S) -> xT (S,C) bf16 ----------------
__global__ __launch_bounds__(256)
void transpose_cast_x_kernel(const float* __restrict__ x, unsigned short* __restrict__ xT) {
  __shared__ float t[32][33];
  int st = blockIdx.x, ct = blockIdx.y;
  int c = threadIdx.x & 31, rq = threadIdx.x >> 5;
#pragma unroll
  for (int i = 0; i < 4; ++i) {
    int r = rq + i * 8;
    t[r][c] = x[(size_t)(ct * 32 + r) * S_LEN + st * 32 + c];
  }
  __syncthreads();
#pragma unroll
  for (int i = 0; i < 4; ++i) {
    int r = rq + i * 8;
    xT[(size_t)(st * 32 + r) * C_DIM + ct * 32 + c] = f2bf(t[c][r]);
  }
}

// ============ GEMM core: 128(M)x64(N), BK=64, A direct global->VGPR =========
// Waves tile M only: wave w owns rows [m0+w*32, +32), all 64 N-cols.
// A-frag (32x32x16 A-operand): lane reads row m0+w*32+l31, 16B at k=kb*16+half*8
//   -> no LDS round-trip for A (private to wave).
// B staged in LDS (shared by 4 waves), XOR-swizzled, register-prefetch dbuf.
// acc[ni] (ni=0,1): C/D 32x32 layout: col = n0+ni*32+l31,
//   row = m0+wave*32 + (reg&3)+8*(reg>>2)+4*half.

#define GEMM_CORE(A_, BT_, m0_, n0_)                                            \
  int tid = threadIdx.x, wave = tid >> 6, lane = tid & 63;                      \
  int l31 = lane & 31, half = lane >> 5;                                        \
  const unsigned short* Arow = A_ + (size_t)(m0_ + wave * 32 + l31) * C_DIM + half * 8; \
  int br = tid >> 3, bc = tid & 7;                                              \
  int bpos = (bc ^ (br & 7)) * 8;                                               \
  const unsigned short* Bg = BT_ + (size_t)n0_ * C_DIM;                         \
  floatx16 acc[2];                                                              \
  acc[0] = (floatx16)0.f; acc[1] = (floatx16)0.f;                               \
  bf16x8 aC[4], aN[4];                                                          \
  ushortx8 rB[2];                                                               \
  auto loadA = [&](int kt, bf16x8(&af)[4]) {                                    \
    _Pragma("unroll")                                                           \
    for (int kb = 0; kb < 4; ++kb)                                              \
      af[kb] = *(const bf16x8*)(Arow + kt + kb * 16);                           \
  };                                                                            \
  auto loadB = [&](int kt) {                                                    \
    _Pragma("unroll")                                                           \
    for (int i = 0; i < 2; ++i)                                                 \
      rB[i] = *(const ushortx8*)(Bg + (size_t)(i * 32 + br) * C_DIM + kt + bc * 8); \
  };                                                                            \
  auto storeB = [&](int b) {                                                    \
    _Pragma("unroll")                                                           \
    for (int i = 0; i < 2; ++i)                                                 \
      *(ushortx8*)&Bsm[b][(i * 32 + br) * 64 + bpos] = rB[i];                   \
  };                                                                            \
  auto compute = [&](int b, bf16x8(&af)[4]) {                                   \
    _Pragma("unroll")                                                           \
    for (int kb = 0; kb < 4; ++kb) {                                            \
      int co = ((((kb << 1) | half)) ^ (l31 & 7)) << 3;                         \
      bf16x8 b0 = *(const bf16x8*)&Bsm[b][l31 * 64 + co];                       \
      bf16x8 b1 = *(const bf16x8*)&Bsm[b][(32 + l31) * 64 + co];                \
      acc[0] = __builtin_amdgcn_mfma_f32_32x32x16_bf16(af[kb], b0, acc[0], 0, 0, 0); \
      acc[1] = __builtin_amdgcn_mfma_f32_32x32x16_bf16(af[kb], b1, acc[1], 0, 0, 0); \
    }                                                                           \
  };                                                                            \
  loadA(0, aC); loadB(0); storeB(0);                                            \
  __syncthreads();                                                              \
  for (int t = 0; t < 32; t += 2) {                                             \
    loadA((t + 1) * 64, aN); loadB((t + 1) * 64);                               \
    compute(0, aC);                                                             \
    storeB(1);                                                                  \
    __syncthreads();                                                            \
    if (t < 30) { loadA((t + 2) * 64, aC); loadB((t + 2) * 64); }               \
    compute(1, aN);                                                             \
    if (t < 30) storeB(0);                                                      \
    __syncthreads();                                                            \
  }

// ---------------- QKV GEMM + fused rmsnorm/rope/sigmoid epilogue ------------
// Grid dim3(40,16): x = M-tile (40%8==0 -> same-XCD A reuse across N-blocks).
__global__ __launch_bounds__(256, 4)
void gemm_qkv_fused(const unsigned short* __restrict__ A,
                    const unsigned short* __restrict__ BT,
                    const float* __restrict__ qw, const float* __restrict__ kw,
                    const int* __restrict__ pos_ids,
                    const float* __restrict__ cosc, const float* __restrict__ sinc,
                    unsigned short* __restrict__ qb, unsigned short* __restrict__ kbuf,
                    unsigned short* __restrict__ vTb, unsigned short* __restrict__ sgb) {
  __shared__ unsigned short Bsm[2][64 * 64];
  __shared__ float pp[4][2][32];
  int m0 = blockIdx.x * 128, n0 = blockIdx.y * 64;
  GEMM_CORE(A, BT, m0, n0)

  int ty = blockIdx.x;
  if (ty < 32 && (ty & 1) == 0 || (ty >= 32 && ty < 36)) {
    // ---- rmsnorm + rope (q head or k head) ----
    const float* w = (ty < 32) ? qw : kw;
    unsigned short* outp = (ty < 32)
        ? qb + (size_t)(ty >> 1) * S_LEN * HD
        : kbuf + (size_t)(ty - 32) * S_LEN * HD;
    float ss[2];
#pragma unroll
    for (int ni = 0; ni < 2; ++ni) {
      float s = 0.f;
#pragma unroll
      for (int reg = 0; reg < 16; ++reg) { float v = acc[ni][reg]; s += v * v; }
      s += __shfl_xor(s, 32);  // other half: disjoint 16 rows, same column
      ss[ni] = s;
    }
    if (half == 0) { pp[wave][0][l31] = ss[0]; pp[wave][1][l31] = ss[1]; }
    __syncthreads();
#pragma unroll
    for (int ni = 0; ni < 2; ++ni) {
      float rn = rsqrtf((pp[0][ni][l31] + pp[1][ni][l31] + pp[2][ni][l31] + pp[3][ni][l31])
                        * (1.0f / 128.0f) + 1e-6f);
      int scol = n0 + ni * 32 + l31;
      int pos = pos_ids[scol];
      bool rope = (wave == 0);  // rows 0..31 = d 0..31
#pragma unroll
      for (int g = 0; g < 4; ++g) {
        int dbase = wave * 32 + half * 4 + g * 8;
        ushort4 o;
#pragma unroll
        for (int rr = 0; rr < 4; ++rr) {
          int reg = g * 4 + rr;
          int d = dbase + rr;
          float v = acc[ni][reg] * rn * (1.0f + w[d]);
          if (rope) {
            float cv = cosc[pos * ROT + d], sv = sinc[pos * ROT + d];
            int d2 = (d < 16) ? d + 16 : d - 16;
            float pv = acc[ni][reg ^ 8] * rn * (1.0f + w[d2]);
            v = v * cv + ((d < 16) ? -pv : pv) * sv;
          }
          ((unsigned short*)&o)[rr] = f2bf(v);
        }
        *(ushort4*)&outp[(size_t)scol * HD + dbase] = o;
      }
    }
  } else if (ty < 32) {
    // ---- gate: sigmoid -> sgb (h,S,D) bf16 ----
    int h = ty >> 1;
#pragma unroll
    for (int ni = 0; ni < 2; ++ni) {
      int scol = n0 + ni * 32 + l31;
#pragma unroll
      for (int g = 0; g < 4; ++g) {
        int dbase = wave * 32 + half * 4 + g * 8;
        ushort4 o;
#pragma unroll
        for (int rr = 0; rr < 4; ++rr)
          ((unsigned short*)&o)[rr] = f2bf(1.0f / (1.0f + __expf(-acc[ni][g * 4 + rr])));
        *(ushort4*)&sgb[((size_t)h * S_LEN + scol) * HD + dbase] = o;
      }
    }
  } else {
    // ---- v: rows are d, cols are s -> vTb (hk,D,S) ----
    int hk = ty - 36;
#pragma unroll
    for (int ni = 0; ni < 2; ++ni) {
      int scol = n0 + ni * 32 + l31;
#pragma unroll
      for (int reg = 0; reg < 16; ++reg) {
        int d = wave * 32 + (reg & 3) + 8 * (reg >> 2) + 4 * half;
        vTb[(size_t)hk * HD * S_LEN + (size_t)d * S_LEN + scol] = f2bf(acc[ni][reg]);
      }
    }
  }
}

// ---------------- O-proj GEMM, same core, direct f32 out --------------------
// Grid dim3(16,16) = 256 blocks = exactly 1/CU, all co-resident.
__global__ __launch_bounds__(256, 4)
void gemm_oproj(const unsigned short* __restrict__ A,
                const unsigned short* __restrict__ BT,
                float* __restrict__ C) {
  __shared__ unsigned short Bsm[2][64 * 64];
  int m0 = blockIdx.x * 128, n0 = blockIdx.y * 64;
  GEMM_CORE(A, BT, m0, n0)
#pragma unroll
  for (int ni = 0; ni < 2; ++ni) {
    int col = n0 + ni * 32 + l31;
#pragma unroll
    for (int reg = 0; reg < 16; ++reg) {
      int row = m0 + wave * 32 + (reg & 3) + 8 * (reg >> 2) + 4 * half;
      C[(size_t)row * S_LEN + col] = acc[ni][reg];
    }
  }
}

// ---------------- MFMA flash attention, LDS-staged, 64 queries/block --------
__global__ __launch_bounds__(256)
void attn_kernel(const unsigned short* __restrict__ qb,
                 const unsigned short* __restrict__ kbuf,
                 const unsigned short* __restrict__ vTb,
                 const unsigned short* __restrict__ sgb,
                 unsigned short* __restrict__ outT) {
  __shared__ __align__(16) unsigned short Ks[64 * 128];   // [key][d], swizzled
  __shared__ __align__(16) unsigned short Vs[128 * 64];   // [d][key], swizzled
  __shared__ __align__(16) unsigned short Ps[4][16][72];
  int h = blockIdx.x, qt = blockIdx.y;
  int s0 = qt * 64;
  int hk = h >> 2;
  int tid = threadIdx.x, wave = tid >> 6, lane = tid & 63;
  int l16 = lane & 15, quad = lane >> 4;
  int lsw = l16 & 7;

  const unsigned short* qg = qb + ((size_t)(h * S_LEN + s0 + wave * 16 + l16)) * HD;
  bf16x8 qfr[4];
#pragma unroll
  for (int kb = 0; kb < 4; ++kb)
    qfr[kb] = *(const bf16x8*)(qg + kb * 32 + quad * 8);

  float m_r[4], l_r[4];
#pragma unroll
  for (int r = 0; r < 4; ++r) { m_r[r] = -1e30f; l_r[r] = 0.f; }
  floatx4 acc_o[8];
#pragma unroll
  for (int i = 0; i < 8; ++i) acc_o[i] = (floatx4)0.f;
  int srow_base = s0 + wave * 16 + quad * 4;

  const unsigned short* kg0 = kbuf + (size_t)hk * S_LEN * HD;
  const unsigned short* vg0 = vTb + (size_t)hk * HD * S_LEN;

  int kr4 = lane >> 4, kc16 = lane & 15;
  int vr8 = lane >> 3, vc8 = lane & 7;

  for (int t = 0; t <= qt; ++t) {
    int jt = t * 64;
#pragma unroll
    for (int i = 0; i < 4; ++i) {
      int rbase = wave * 16 + i * 4;
      int row = rbase + kr4;
      int cs = kc16 ^ (row & 7);
      async_copy16(kg0 + (size_t)(jt + row) * HD + cs * 8, Ks + rbase * 128);
    }
#pragma unroll
    for (int i = 0; i < 4; ++i) {
      int rbase = wave * 32 + i * 8;
      int row = rbase + vr8;
      int cs = vc8 ^ (row & 7);
      async_copy16(vg0 + (size_t)row * S_LEN + jt + cs * 8, Vs + rbase * 64);
    }
    __syncthreads();

    floatx4 acc_s[4];
#pragma unroll
    for (int ni = 0; ni < 4; ++ni) acc_s[ni] = (floatx4)0.f;
#pragma unroll
    for (int kb = 0; kb < 4; ++kb) {
#pragma unroll
      for (int ni = 0; ni < 4; ++ni) {
        int cl = (kb * 4 + quad) ^ lsw;
        bf16x8 bk = *(const bf16x8*)&Ks[(ni * 16 + l16) * 128 + cl * 8];
        acc_s[ni] = __builtin_amdgcn_mfma_f32_16x16x32_bf16(qfr[kb], bk, acc_s[ni], 0, 0, 0);
      }
    }

    bool diag = (t == qt);
    float alpha[4];
#pragma unroll
    for (int r = 0; r < 4; ++r) {
      float scv[4];
      float mx = -1e30f;
#pragma unroll
      for (int ni = 0; ni < 4; ++ni) {
        float sv = acc_s[ni][r] * SCALE;
        if (diag) {
          int jg = jt + ni * 16 + l16;
          if (jg > srow_base + r) sv = -1e30f;
        }
        scv[ni] = sv;
        mx = fmaxf(mx, sv);
      }
#pragma unroll
      for (int off = 8; off; off >>= 1) mx = fmaxf(mx, __shfl_xor(mx, off, 16));
      float mnew = fmaxf(m_r[r], mx);
      float psv = 0.f;
#pragma unroll
      for (int ni = 0; ni < 4; ++ni) {
        float pv = (scv[ni] > -1e29f) ? __expf(scv[ni] - mnew) : 0.f;
        Ps[wave][quad * 4 + r][ni * 16 + l16] = f2bf(pv);
        psv += pv;
      }
#pragma unroll
      for (int off = 8; off; off >>= 1) psv += __shfl_xor(psv, off, 16);
      alpha[r] = __expf(m_r[r] - mnew);
      m_r[r] = mnew;
      l_r[r] = l_r[r] * alpha[r] + psv;
    }
#pragma unroll
    for (int i = 0; i < 8; ++i)
#pragma unroll
      for (int r = 0; r < 4; ++r) acc_o[i][r] *= alpha[r];
    __threadfence_block();

#pragma unroll
    for (int kb2 = 0; kb2 < 2; ++kb2) {
      bf16x8 ap = *(const bf16x8*)&Ps[wave][l16][kb2 * 32 + quad * 8];
#pragma unroll
      for (int ni2 = 0; ni2 < 8; ++ni2) {
        int cl = (kb2 * 4 + quad) ^ lsw;
        bf16x8 bv = *(const bf16x8*)&Vs[(ni2 * 16 + l16) * 64 + cl * 8];
        acc_o[ni2] = __builtin_amdgcn_mfma_f32_16x16x32_bf16(ap, bv, acc_o[ni2], 0, 0, 0);
      }
    }
    __syncthreads();
  }

#pragma unroll
  for (int r = 0; r < 4; ++r) {
    int s = srow_base + r;
    float inv = 1.0f / l_r[r];
    const unsigned short* sgp = sgb + ((size_t)h * S_LEN + s) * HD;
    unsigned short* op = outT + (size_t)s * (NH * HD) + h * HD;
#pragma unroll
    for (int ni2 = 0; ni2 < 8; ++ni2) {
      int d = ni2 * 16 + l16;
      op[d] = f2bf(acc_o[ni2][r] * inv * bf2f(sgp[d]));
    }
  }
}

// ---------------- host launch ----------------
extern "C" void kernel_launch(void* const* d_in, const int* in_sizes, int n_in,
                              void* d_out, int out_size, void* d_ws, size_t ws_size,
                              hipStream_t stream) {
  const float* hs       = (const float*)d_in[0];
  const float* q_proj_w = (const float*)d_in[1];
  const float* k_proj_w = (const float*)d_in[2];
  const float* v_proj_w = (const float*)d_in[3];
  const float* o_proj_w = (const float*)d_in[4];
  const float* q_norm_w = (const float*)d_in[5];
  const float* k_norm_w = (const float*)d_in[6];
  const int*   pos_ids  = (const int*)d_in[9];
  const float* cos_c    = (const float*)d_in[10];
  const float* sin_c    = (const float*)d_in[11];
  float* out = (float*)d_out;

  char* ws = (char*)d_ws;
  unsigned short* wqkv = (unsigned short*)(ws + 0);            // 5120x2048 bf16
  unsigned short* wo   = (unsigned short*)(ws + 20971520);     // 2048x2048 bf16
  unsigned short* xT   = (unsigned short*)(ws + 29360128);     // 1024x2048 bf16
  unsigned short* qb   = (unsigned short*)(ws + 33554432);     // 16x1024x128
  unsigned short* kbuf = (unsigned short*)(ws + 37748736);     // 4x1024x128
  unsigned short* vTb  = (unsigned short*)(ws + 38797312);     // 4x128x1024 (V^T)
  unsigned short* sgb  = (unsigned short*)(ws + 39845888);     // 16x1024x128
  unsigned short* aoT  = (unsigned short*)(ws + 44040192);     // 1024x2048

  cast_all_kernel<<<14336, 256, 0, stream>>>(q_proj_w, k_proj_w, v_proj_w, o_proj_w, wqkv);
  transpose_cast_x_kernel<<<dim3(32, 64), 256, 0, stream>>>(hs, xT);
  gemm_qkv_fused<<<dim3(40, 16), 256, 0, stream>>>(wqkv, xT, q_norm_w, k_norm_w,
                                                   pos_ids, cos_c, sin_c,
                                                   qb, kbuf, vTb, sgb);
  attn_kernel<<<dim3(16, 16), 256, 0, stream>>>(qb, kbuf, vTb, sgb, aoT);
  gemm_oproj<<<dim3(16, 16), 256, 0, stream>>>(wo, aoT, out);
}